// Round 10
// baseline (85.785 us; speedup 1.0000x reference)
//
#include <hip/hip_runtime.h>
#include <math.h>

#define NPATCH 128
#define CH 8              // channels per patch = L / N_PATCHES
#define D 64
#define G 8               // query patches per block
#define NQ (G*CH)         // 64 queries/block
#define NKEY 128          // staged key slots
#define KSTR 72           // f16 strides: 72,136 ≡ 4 (mod 8) dwords; 100 -> 2-way max
#define VSTR 136
#define PSTR 100          // per-wave-relative P row: 96 keys + pad

typedef __fp16 half8 __attribute__((ext_vector_type(8)));
typedef __fp16 h2    __attribute__((ext_vector_type(2)));
typedef float  f32x4 __attribute__((ext_vector_type(4)));
typedef unsigned u32x4 __attribute__((ext_vector_type(4)));

static __device__ __forceinline__ unsigned pk(float x, float y) {
    return __builtin_bit_cast(unsigned, __builtin_amdgcn_cvt_pkrtz(x, y));
}
static __device__ __forceinline__ h2 pk2(float x, float y) {
    return __builtin_amdgcn_cvt_pkrtz(x, y);
}
static __device__ __forceinline__ h2 pkmax(h2 a, h2 b) {
    h2 r; r[0] = a[0] > b[0] ? a[0] : b[0]; r[1] = a[1] > b[1] ? a[1] : b[1]; return r;
}
static __device__ __forceinline__ h2 shfl_h2(h2 v, int off) {
    return __builtin_bit_cast(h2, __shfl_xor(__builtin_bit_cast(int, v), off));
}
static __device__ __forceinline__ half8 ld8(const unsigned short* p) {
    return __builtin_bit_cast(half8, *(const u32x4*)p);
}
static __device__ __forceinline__ half8 mk8(const float4& a, const float4& b) {
    u32x4 u = { pk(a.x, a.y), pk(a.z, a.w), pk(b.x, b.y), pk(b.z, b.w) };
    return __builtin_bit_cast(half8, u);
}

__global__ __launch_bounds__(256) void signed_attn_kernel(
    const float* __restrict__ Q, const float* __restrict__ K,
    const float* __restrict__ V, const float* __restrict__ logscale,
    float* __restrict__ O)
{
    __shared__ __align__(16) unsigned short sK[NKEY * KSTR];   // 18432 B
    __shared__ __align__(16) unsigned short sVt[D * VSTR];     // 17408 B (V transposed)
    __shared__ __align__(16) unsigned short sP[NQ * PSTR];     // 12800 B (wave-relative)
    // total 48640 B (grid-limited to 2 blocks/CU anyway)

    const int tid = threadIdx.x;
    const int grp = blockIdx.x & 15;          // 16 patch-groups
    const int bh  = blockIdx.x >> 4;
    const int p0  = grp * G;

    const long long base = (long long)bh * (NPATCH * CH) * D;
    const int nst = min(NKEY, (NPATCH - 1 - p0) * CH);   // valid staged keys

    const float scale = fminf(fmaxf(__expf(logscale[0]), 1.0f), 30.0f) * 0.125f;

    const int wav = tid >> 6, lane = tid & 63;
    const int col = lane & 15, quad = lane >> 4;

    // ---- Q A-frags straight from global (issued first; L1/HBM overlap with K) ----
    const float4* Qg4 = (const float4*)(Q + base + (long long)(p0 * CH + wav * 16 + col) * D);
    const float4 q00 = Qg4[quad * 2],     q01 = Qg4[quad * 2 + 1];
    const float4 q10 = Qg4[8 + quad * 2], q11 = Qg4[9 + quad * 2];

    // ---- V prefetch into registers (in flight through barrier1 + QK + softmax) ----
    const float4* Vg = (const float4*)(V + base + (long long)((p0 + 1) * CH) * D);
    float4 va[4], vb[4];
#pragma unroll
    for (int it = 0; it < 4; ++it) {
        const int u = tid + it * 256;                     // (keypair u&63, dim-quad u>>6)
        const int kp = u & 63;
        va[it] = make_float4(0.f, 0.f, 0.f, 0.f);
        vb[it] = va[it];
        if (2 * kp < nst) { va[it] = Vg[(2 * kp) * 16 + (u >> 6)];
                            vb[it] = Vg[(2 * kp + 1) * 16 + (u >> 6)]; }
    }

    // ---- stage K [key][d] f16 (zero tail) ----
    {
        const float4* Kg = (const float4*)(K + base + (long long)((p0 + 1) * CH) * D);
#pragma unroll
        for (int it = 0; it < 8; ++it) {
            const int i = tid + it * 256;
            const int row = i >> 4, d4 = i & 15;
            uint2 w = make_uint2(0u, 0u);
            if (row < nst) { const float4 v = Kg[i]; w = make_uint2(pk(v.x, v.y), pk(v.z, v.w)); }
            *(uint2*)&sK[row * KSTR + d4 * 4] = w;
        }
    }
    __syncthreads();   // barrier 1: sK ready (V loads still in flight)

    const half8 a0 = mk8(q00, q01);                       // d = 8q..8q+7
    const half8 a1 = mk8(q10, q11);                       // d = 32+8q..+7

    // ---- QK^T: wave w needs keys [16w, 16w+80) -> 5 n-tiles ----
    f32x4 acc[5];
#pragma unroll
    for (int t = 0; t < 5; ++t) acc[t] = (f32x4){0.f, 0.f, 0.f, 0.f};
#pragma unroll
    for (int t = 0; t < 5; ++t) {
        const int krow = (wav + t) * 16 + col;
        const half8 b0 = ld8(&sK[krow * KSTR + quad * 8]);
        const half8 b1 = ld8(&sK[krow * KSTR + 32 + quad * 8]);
        acc[t] = __builtin_amdgcn_mfma_f32_16x16x32_f16(a0, b0, acc[t], 0, 0, 0);
        acc[t] = __builtin_amdgcn_mfma_f32_16x16x32_f16(a1, b1, acc[t], 0, 0, 0);
    }

    // ---- dual softmax (packed-f16 butterflies over lane bits 0..3) ----
#pragma unroll
    for (int r = 0; r < 4; ++r) {
        const int q   = wav * 16 + quad * 4 + r;          // block-local query
        const int kr0 = (q >> 3) * 8;                     // window start (16w or 16w+8)
        const int kmx = min(kr0 + 72, nst);

        float tv[5]; bool vl[5];
        float mpl = -1e30f, mnl = -1e30f;
#pragma unroll
        for (int t = 0; t < 5; ++t) {
            const int c = (wav + t) * 16 + col;
            tv[t] = scale * acc[t][r];
            vl[t] = (c >= kr0) && (c < kmx);
            mpl = fmaxf(mpl, vl[t] ?  tv[t] : -1e30f);
            mnl = fmaxf(mnl, vl[t] ? -tv[t] : -1e30f);
        }
        h2 pm = pk2(mpl, mnl);                            // RTZ clamps -1e30 to finite -65504
#pragma unroll
        for (int off = 1; off < 16; off <<= 1) pm = pkmax(pm, shfl_h2(pm, off));
        const float mp = (float)pm[0], mn = (float)pm[1]; // shift-invariance: f16 max is fine

        float ep[5], en[5], spl = 0.f, snl = 0.f;
#pragma unroll
        for (int t = 0; t < 5; ++t) {
            ep[t] = vl[t] ? __expf( tv[t] - mp) : 0.f;
            en[t] = vl[t] ? __expf(-tv[t] - mn) : 0.f;
            spl += ep[t]; snl += en[t];
        }
        h2 ss = pk2(spl, snl);
#pragma unroll
        for (int off = 1; off < 16; off <<= 1) ss = ss + shfl_h2(ss, off);
        const float sp = (float)ss[0], sn = (float)ss[1];
        const float rp = (sp > 0.f) ? 1.f / sp : 0.f;     // fully-masked row -> P = 0
        const float rn = (sn > 0.f) ? 1.f / sn : 0.f;
#pragma unroll
        for (int t = 0; t < 5; ++t) {                     // rel col = 16t+col
            const float A = ep[t] * rp - en[t] * rn;      // invalid -> exact 0
            sP[q * PSTR + t * 16 + col] = (unsigned short)pk(A, A);
        }
        sP[q * PSTR + 80 + col] = 0;                      // zero-pad rel cols 80..95
    }

    // ---- V convert + sVt[d][key] writes (loads should have landed by now) ----
#pragma unroll
    for (int it = 0; it < 4; ++it) {
        const int u = tid + it * 256;
        const int kp = u & 63, dq = u >> 6;
        *(unsigned*)&sVt[(dq * 4 + 0) * VSTR + 2 * kp] = pk(va[it].x, vb[it].x);
        *(unsigned*)&sVt[(dq * 4 + 1) * VSTR + 2 * kp] = pk(va[it].y, vb[it].y);
        *(unsigned*)&sVt[(dq * 4 + 2) * VSTR + 2 * kp] = pk(va[it].z, vb[it].z);
        *(unsigned*)&sVt[(dq * 4 + 3) * VSTR + 2 * kp] = pk(va[it].w, vb[it].w);
    }
    __syncthreads();   // barrier 2: sVt ready (also orders sP, though sP is wave-private)

    // ---- PV: O[16 x 64] = P[16 x 96] * Vt^T (abs key = 16w + rel) ----
    f32x4 oc[4];
#pragma unroll
    for (int t = 0; t < 4; ++t) oc[t] = (f32x4){0.f, 0.f, 0.f, 0.f};
#pragma unroll
    for (int kq = 0; kq < 3; ++kq) {
        const half8 ap = ld8(&sP[(wav * 16 + col) * PSTR + kq * 32 + quad * 8]);
        // clamp into the WRITTEN region of sVt; clamped lanes have P==0
        const int kb = wav * 16 + kq * 32 + quad * 8;
        const int kcl = (kb <= 120) ? kb : 120;
#pragma unroll
        for (int t = 0; t < 4; ++t) {
            const half8 bv = ld8(&sVt[(t * 16 + col) * VSTR + kcl]);
            oc[t] = __builtin_amdgcn_mfma_f32_16x16x32_f16(ap, bv, oc[t], 0, 0, 0);
        }
    }

    // ---- store O: lane holds rows quad*4+r, cols col+16t ----
    float* Ob = O + base + (long long)(p0 * CH) * D;
#pragma unroll
    for (int t = 0; t < 4; ++t) {
#pragma unroll
        for (int r = 0; r < 4; ++r) {
            Ob[(wav * 16 + quad * 4 + r) * D + t * 16 + col] = oc[t][r];
        }
    }
}

extern "C" void kernel_launch(void* const* d_in, const int* in_sizes, int n_in,
                              void* d_out, int out_size, void* d_ws, size_t ws_size,
                              hipStream_t stream) {
    const float* Q  = (const float*)d_in[0];
    const float* K  = (const float*)d_in[1];
    const float* V  = (const float*)d_in[2];
    const float* ls = (const float*)d_in[3];
    float* O = (float*)d_out;

    const int L = 1024;
    const int nBH = in_sizes[0] / (L * D);    // B*H = 32
    dim3 grid(nBH * (NPATCH / G));            // 512 blocks
    signed_attn_kernel<<<grid, 256, 0, stream>>>(Q, K, V, ls, O);
}

// Round 11
// 85.732 us; speedup vs baseline: 1.0006x; 1.0006x over previous
//
#include <hip/hip_runtime.h>
#include <math.h>

#define NPATCH 128
#define CH 8              // channels per patch = L / N_PATCHES
#define D 64
#define G 4               // query patches per block
#define NQ (G*CH)         // 32 queries/block
#define NKEY 96           // staged key slots = (G+9-1)*CH
#define KSTR 72           // f16 strides: 72/104 -> 16B-aligned rows, 2-way max aliasing
#define VSTR 104
#define PSTR 100          // wave-relative P row: 80 keys + 16 pad (+4 slack)

typedef __fp16 half8 __attribute__((ext_vector_type(8)));
typedef float  f32x4 __attribute__((ext_vector_type(4)));
typedef unsigned u32x4 __attribute__((ext_vector_type(4)));

static __device__ __forceinline__ unsigned pk(float x, float y) {
    return __builtin_bit_cast(unsigned, __builtin_amdgcn_cvt_pkrtz(x, y));
}
static __device__ __forceinline__ half8 ld8(const unsigned short* p) {
    return __builtin_bit_cast(half8, *(const u32x4*)p);
}
static __device__ __forceinline__ half8 mk8(const float4& a, const float4& b) {
    u32x4 u = { pk(a.x, a.y), pk(a.z, a.w), pk(b.x, b.y), pk(b.z, b.w) };
    return __builtin_bit_cast(half8, u);
}

__global__ __launch_bounds__(128) void signed_attn_kernel(
    const float* __restrict__ Q, const float* __restrict__ K,
    const float* __restrict__ V, const float* __restrict__ logscale,
    float* __restrict__ O)
{
    __shared__ __align__(16) unsigned short sK[NKEY * KSTR];   // 13824 B
    __shared__ __align__(16) unsigned short sVt[D * VSTR];     // 13312 B (V transposed)
    __shared__ __align__(16) unsigned short sP[NQ * PSTR];     //  6400 B (wave-relative)
    // total 33536 B -> 4 blocks/CU (134 KB), 1024 blocks, 4 staging streams/CU

    const int tid = threadIdx.x;
    const int grp = blockIdx.x & 31;          // 32 patch-groups
    const int bh  = blockIdx.x >> 5;
    const int p0  = grp * G;

    const long long base = (long long)bh * (NPATCH * CH) * D;
    const int nst = min(NKEY, (NPATCH - 1 - p0) * CH);   // valid staged keys (mult of 8)

    const float scale = fminf(fmaxf(__expf(logscale[0]), 1.0f), 30.0f) * 0.125f;

    const int wav = tid >> 6, lane = tid & 63;            // 2 waves/block
    const int col = lane & 15, quad = lane >> 4;

    // ---- Q A-frags straight from global (issued first; overlap with staging) ----
    const float4* Qg4 = (const float4*)(Q + base + (long long)(p0 * CH + wav * 16 + col) * D);
    const float4 q00 = Qg4[quad * 2],     q01 = Qg4[quad * 2 + 1];
    const float4 q10 = Qg4[8 + quad * 2], q11 = Qg4[9 + quad * 2];

    // ---- stage K [key][d] f16 (zero tail) ----
    {
        const float4* Kg = (const float4*)(K + base + (long long)((p0 + 1) * CH) * D);
#pragma unroll
        for (int it = 0; it < 12; ++it) {
            const int i = tid + it * 128;                 // NKEY*16 = 1536
            const int row = i >> 4, d4 = i & 15;
            uint2 w = make_uint2(0u, 0u);
            if (row < nst) { const float4 v = Kg[i]; w = make_uint2(pk(v.x, v.y), pk(v.z, v.w)); }
            *(uint2*)&sK[row * KSTR + d4 * 4] = w;
        }
    }
    // ---- stage V transposed Vt[d][key], key-pairs per dword (zero tail) ----
    {
        const float4* Vg = (const float4*)(V + base + (long long)((p0 + 1) * CH) * D);
#pragma unroll
        for (int it = 0; it < 6; ++it) {
            const int u = tid + it * 128;                 // 16 dq x 48 keypairs = 768
            const int dq = u / 48, kp = u - dq * 48;
            float4 va = make_float4(0.f, 0.f, 0.f, 0.f);
            float4 vb = va;
            if (2 * kp < nst) { va = Vg[(2 * kp) * 16 + dq]; vb = Vg[(2 * kp + 1) * 16 + dq]; }
            *(unsigned*)&sVt[(dq * 4 + 0) * VSTR + 2 * kp] = pk(va.x, vb.x);
            *(unsigned*)&sVt[(dq * 4 + 1) * VSTR + 2 * kp] = pk(va.y, vb.y);
            *(unsigned*)&sVt[(dq * 4 + 2) * VSTR + 2 * kp] = pk(va.z, vb.z);
            *(unsigned*)&sVt[(dq * 4 + 3) * VSTR + 2 * kp] = pk(va.w, vb.w);
        }
    }
    __syncthreads();   // the only barrier

    const half8 a0 = mk8(q00, q01);                       // d = 8q..8q+7
    const half8 a1 = mk8(q10, q11);                       // d = 32+8q..+7

    // ---- QK^T: wave w needs rel keys [16w, 16w+80) -> 5 n-tiles ----
    f32x4 acc[5];
#pragma unroll
    for (int t = 0; t < 5; ++t) acc[t] = (f32x4){0.f, 0.f, 0.f, 0.f};
#pragma unroll
    for (int t = 0; t < 5; ++t) {
        const int krow = (wav + t) * 16 + col;            // max 95 < NKEY
        const half8 b0 = ld8(&sK[krow * KSTR + quad * 8]);
        const half8 b1 = ld8(&sK[krow * KSTR + 32 + quad * 8]);
        acc[t] = __builtin_amdgcn_mfma_f32_16x16x32_f16(a0, b0, acc[t], 0, 0, 0);
        acc[t] = __builtin_amdgcn_mfma_f32_16x16x32_f16(a1, b1, acc[t], 0, 0, 0);
    }

    // ---- dual softmax: lane holds rows quad*4+r, abs cols 16(w+t)+col ----
#pragma unroll
    for (int r = 0; r < 4; ++r) {
        const int q   = wav * 16 + quad * 4 + r;          // block-local query (0..31)
        const int kr0 = (q >> 3) * 8;                     // window start in staged keys
        const int kmx = min(kr0 + 72, nst);

        float tv[5]; bool vl[5];
        float mp = -1e30f, mn = -1e30f;
#pragma unroll
        for (int t = 0; t < 5; ++t) {
            const int c = (wav + t) * 16 + col;
            tv[t] = scale * acc[t][r];
            vl[t] = (c >= kr0) && (c < kmx);
            mp = fmaxf(mp, vl[t] ?  tv[t] : -1e30f);
            mn = fmaxf(mn, vl[t] ? -tv[t] : -1e30f);
        }
#pragma unroll
        for (int off = 1; off < 16; off <<= 1) {
            mp = fmaxf(mp, __shfl_xor(mp, off));
            mn = fmaxf(mn, __shfl_xor(mn, off));
        }
        float ep[5], en[5], sp = 0.f, sn = 0.f;
#pragma unroll
        for (int t = 0; t < 5; ++t) {
            ep[t] = vl[t] ? __expf( tv[t] - mp) : 0.f;
            en[t] = vl[t] ? __expf(-tv[t] - mn) : 0.f;
            sp += ep[t]; sn += en[t];
        }
#pragma unroll
        for (int off = 1; off < 16; off <<= 1) {
            sp += __shfl_xor(sp, off);
            sn += __shfl_xor(sn, off);
        }
        const float rp = (sp > 0.f) ? 1.f / sp : 0.f;     // fully-masked row -> P = 0
        const float rn = (sn > 0.f) ? 1.f / sn : 0.f;
#pragma unroll
        for (int t = 0; t < 5; ++t) {                     // rel col = 16t+col
            const float A = ep[t] * rp - en[t] * rn;      // invalid -> exact 0
            sP[q * PSTR + t * 16 + col] = (unsigned short)pk(A, A);
        }
        sP[q * PSTR + 80 + col] = 0;                      // zero-pad rel cols 80..95
    }
    // wave reads back only its own 16 P rows -> no barrier needed

    // ---- PV: O[16 x 64] = P[16 x 96] * Vt^T (abs key = 16w + rel) ----
    f32x4 oc[4];
#pragma unroll
    for (int t = 0; t < 4; ++t) oc[t] = (f32x4){0.f, 0.f, 0.f, 0.f};
#pragma unroll
    for (int kq = 0; kq < 3; ++kq) {
        const half8 ap = ld8(&sP[(wav * 16 + col) * PSTR + kq * 32 + quad * 8]);
        // clamp into the WRITTEN region of sVt (keys < NKEY); clamped lanes have P==0
        const int kb = wav * 16 + kq * 32 + quad * 8;     // max 104
        const int kcl = (kb <= NKEY - 8) ? kb : (NKEY - 8);
#pragma unroll
        for (int t = 0; t < 4; ++t) {
            const half8 bv = ld8(&sVt[(t * 16 + col) * VSTR + kcl]);
            oc[t] = __builtin_amdgcn_mfma_f32_16x16x32_f16(ap, bv, oc[t], 0, 0, 0);
        }
    }

    // ---- store O: lane holds rows quad*4+r, cols col+16t ----
    float* Ob = O + base + (long long)(p0 * CH) * D;
#pragma unroll
    for (int t = 0; t < 4; ++t) {
#pragma unroll
        for (int r = 0; r < 4; ++r) {
            Ob[(wav * 16 + quad * 4 + r) * D + t * 16 + col] = oc[t][r];
        }
    }
}

extern "C" void kernel_launch(void* const* d_in, const int* in_sizes, int n_in,
                              void* d_out, int out_size, void* d_ws, size_t ws_size,
                              hipStream_t stream) {
    const float* Q  = (const float*)d_in[0];
    const float* K  = (const float*)d_in[1];
    const float* V  = (const float*)d_in[2];
    const float* ls = (const float*)d_in[3];
    float* O = (float*)d_out;

    const int L = 1024;
    const int nBH = in_sizes[0] / (L * D);    // B*H = 32
    dim3 grid(nBH * (NPATCH / G));            // 1024 blocks x 128 threads
    signed_attn_kernel<<<grid, 128, 0, stream>>>(Q, K, V, ls, O);
}

// Round 12
// 85.140 us; speedup vs baseline: 1.0076x; 1.0069x over previous
//
#include <hip/hip_runtime.h>
#include <math.h>

#define NPATCH 128
#define CH 8              // channels per patch = L / N_PATCHES
#define D 64
#define G 8               // query patches per block
#define NQ (G*CH)         // 64 queries/block
#define NKEY 128          // key-window slots per block
#define VSTR 136          // f16 strides: ≡ 4 (mod 8) dwords -> 2-way max aliasing
#define PSTR 100          // per-wave-relative P row: 96 keys + pad

typedef __fp16 half8 __attribute__((ext_vector_type(8)));
typedef float  f32x4 __attribute__((ext_vector_type(4)));
typedef unsigned u32x4 __attribute__((ext_vector_type(4)));

static __device__ __forceinline__ unsigned pk(float x, float y) {
    return __builtin_bit_cast(unsigned, __builtin_amdgcn_cvt_pkrtz(x, y));
}
static __device__ __forceinline__ half8 ld8(const unsigned short* p) {
    return __builtin_bit_cast(half8, *(const u32x4*)p);
}
static __device__ __forceinline__ half8 mk8(const float4& a, const float4& b) {
    u32x4 u = { pk(a.x, a.y), pk(a.z, a.w), pk(b.x, b.y), pk(b.z, b.w) };
    return __builtin_bit_cast(half8, u);
}

__global__ __launch_bounds__(256) void signed_attn_kernel(
    const float* __restrict__ Q, const float* __restrict__ K,
    const float* __restrict__ V, const float* __restrict__ logscale,
    float* __restrict__ O)
{
    __shared__ __align__(16) unsigned short sVt[D * VSTR];     // 17408 B (V transposed)
    __shared__ __align__(16) unsigned short sP[NQ * PSTR];     // 12800 B (wave-relative)
    // total 30208 B; no sK — K fragments come straight from global

    const int tid = threadIdx.x;
    const int grp = blockIdx.x & 15;          // 16 patch-groups
    const int bh  = blockIdx.x >> 4;
    const int p0  = grp * G;

    const long long base = (long long)bh * (NPATCH * CH) * D;
    const int nst = min(NKEY, (NPATCH - 1 - p0) * CH);   // valid keys in window

    const float scale = fminf(fmaxf(__expf(logscale[0]), 1.0f), 30.0f) * 0.125f;

    const int wav = tid >> 6, lane = tid & 63;
    const int col = lane & 15, quad = lane >> 4;

    // ---- Q A-frag loads (issued first) ----
    const float4* Qg4 = (const float4*)(Q + base + (long long)(p0 * CH + wav * 16 + col) * D);
    const float4 q00 = Qg4[quad * 2],     q01 = Qg4[quad * 2 + 1];
    const float4 q10 = Qg4[8 + quad * 2], q11 = Qg4[9 + quad * 2];

    // ---- K B-frag loads straight from global: tile t -> row 16(w+t)+col, d-octets ----
    const float4* Kg4 = (const float4*)(K + base + (long long)((p0 + 1) * CH) * D);
    float4 kf[5][4];
#pragma unroll
    for (int t = 0; t < 5; ++t) {
        const int krel = (wav + t) * 16 + col;
        const int kcl  = (krel < nst) ? krel : (nst - 1);   // clamp: finite garbage, masked later
        const float4* Kr = Kg4 + kcl * 16;
        kf[t][0] = Kr[quad * 2];     kf[t][1] = Kr[quad * 2 + 1];      // d = 8q..8q+7
        kf[t][2] = Kr[8 + quad * 2]; kf[t][3] = Kr[9 + quad * 2];      // d = 32+8q..+7
    }

    // ---- stage V transposed Vt[d][key] (zero tail); only consumer of the barrier ----
    {
        const float4* Vg = (const float4*)(V + base + (long long)((p0 + 1) * CH) * D);
#pragma unroll
        for (int it = 0; it < 4; ++it) {
            const int u = tid + it * 256;                   // (keypair u&63, dim-quad u>>6)
            const int kp = u & 63, dq = u >> 6;
            float4 va = make_float4(0.f, 0.f, 0.f, 0.f);
            float4 vb = va;
            if (2 * kp < nst) { va = Vg[(2 * kp) * 16 + dq]; vb = Vg[(2 * kp + 1) * 16 + dq]; }
            *(unsigned*)&sVt[(dq * 4 + 0) * VSTR + 2 * kp] = pk(va.x, vb.x);
            *(unsigned*)&sVt[(dq * 4 + 1) * VSTR + 2 * kp] = pk(va.y, vb.y);
            *(unsigned*)&sVt[(dq * 4 + 2) * VSTR + 2 * kp] = pk(va.z, vb.z);
            *(unsigned*)&sVt[(dq * 4 + 3) * VSTR + 2 * kp] = pk(va.w, vb.w);
        }
    }

    // ---- convert Q/K regs -> f16 frags; QK^T (no barrier needed) ----
    const half8 a0 = mk8(q00, q01);
    const half8 a1 = mk8(q10, q11);

    f32x4 acc[5];
#pragma unroll
    for (int t = 0; t < 5; ++t) acc[t] = (f32x4){0.f, 0.f, 0.f, 0.f};
#pragma unroll
    for (int t = 0; t < 5; ++t) {
        const half8 b0 = mk8(kf[t][0], kf[t][1]);
        const half8 b1 = mk8(kf[t][2], kf[t][3]);
        acc[t] = __builtin_amdgcn_mfma_f32_16x16x32_f16(a0, b0, acc[t], 0, 0, 0);
        acc[t] = __builtin_amdgcn_mfma_f32_16x16x32_f16(a1, b1, acc[t], 0, 0, 0);
    }

    // ---- dual softmax: lane holds rows quad*4+r, abs cols 16(w+t)+col ----
#pragma unroll
    for (int r = 0; r < 4; ++r) {
        const int q   = wav * 16 + quad * 4 + r;          // block-local query
        const int kr0 = (q >> 3) * 8;                     // window start (16w or 16w+8)
        const int kmx = min(kr0 + 72, nst);

        float tv[5]; bool vl[5];
        float mp = -1e30f, mn = -1e30f;
#pragma unroll
        for (int t = 0; t < 5; ++t) {
            const int c = (wav + t) * 16 + col;
            tv[t] = scale * acc[t][r];
            vl[t] = (c >= kr0) && (c < kmx);
            mp = fmaxf(mp, vl[t] ?  tv[t] : -1e30f);
            mn = fmaxf(mn, vl[t] ? -tv[t] : -1e30f);
        }
#pragma unroll
        for (int off = 1; off < 16; off <<= 1) {
            mp = fmaxf(mp, __shfl_xor(mp, off));
            mn = fmaxf(mn, __shfl_xor(mn, off));
        }
        float ep[5], en[5], sp = 0.f, sn = 0.f;
#pragma unroll
        for (int t = 0; t < 5; ++t) {
            ep[t] = vl[t] ? __expf( tv[t] - mp) : 0.f;
            en[t] = vl[t] ? __expf(-tv[t] - mn) : 0.f;
            sp += ep[t]; sn += en[t];
        }
#pragma unroll
        for (int off = 1; off < 16; off <<= 1) {
            sp += __shfl_xor(sp, off);
            sn += __shfl_xor(sn, off);
        }
        const float rp = (sp > 0.f) ? 1.f / sp : 0.f;     // fully-masked row -> P = 0
        const float rn = (sn > 0.f) ? 1.f / sn : 0.f;
#pragma unroll
        for (int t = 0; t < 5; ++t) {                     // rel col = 16t+col
            const float A = ep[t] * rp - en[t] * rn;      // invalid -> exact 0
            sP[q * PSTR + t * 16 + col] = (unsigned short)pk(A, A);
        }
        sP[q * PSTR + 80 + col] = 0;                      // zero-pad rel cols 80..95
    }

    __syncthreads();   // the only barrier: sVt ready (V staged long before, under QK+softmax)

    // ---- PV: O[16 x 64] = P[16 x 96] * Vt^T (abs key = 16w + rel) ----
    f32x4 oc[4];
#pragma unroll
    for (int t = 0; t < 4; ++t) oc[t] = (f32x4){0.f, 0.f, 0.f, 0.f};
#pragma unroll
    for (int kq = 0; kq < 3; ++kq) {
        const half8 ap = ld8(&sP[(wav * 16 + col) * PSTR + kq * 32 + quad * 8]);
        // clamp into the WRITTEN region of sVt; clamped lanes have P==0
        const int kb = wav * 16 + kq * 32 + quad * 8;
        const int kcl = (kb <= 120) ? kb : 120;
#pragma unroll
        for (int t = 0; t < 4; ++t) {
            const half8 bv = ld8(&sVt[(t * 16 + col) * VSTR + kcl]);
            oc[t] = __builtin_amdgcn_mfma_f32_16x16x32_f16(ap, bv, oc[t], 0, 0, 0);
        }
    }

    // ---- store O: lane holds rows quad*4+r, cols col+16t ----
    float* Ob = O + base + (long long)(p0 * CH) * D;
#pragma unroll
    for (int t = 0; t < 4; ++t) {
#pragma unroll
        for (int r = 0; r < 4; ++r) {
            Ob[(wav * 16 + quad * 4 + r) * D + t * 16 + col] = oc[t][r];
        }
    }
}

extern "C" void kernel_launch(void* const* d_in, const int* in_sizes, int n_in,
                              void* d_out, int out_size, void* d_ws, size_t ws_size,
                              hipStream_t stream) {
    const float* Q  = (const float*)d_in[0];
    const float* K  = (const float*)d_in[1];
    const float* V  = (const float*)d_in[2];
    const float* ls = (const float*)d_in[3];
    float* O = (float*)d_out;

    const int L = 1024;
    const int nBH = in_sizes[0] / (L * D);    // B*H = 32
    dim3 grid(nBH * (NPATCH / G));            // 512 blocks
    signed_attn_kernel<<<grid, 256, 0, stream>>>(Q, K, V, ls, O);
}